// Round 1
// baseline (304.713 us; speedup 1.0000x reference)
//
#include <hip/hip_runtime.h>
#include <hip/hip_bf16.h>
#include <stdint.h>

// B=4, T=1024, C=1024, H=16, D=64, ks=16
// wei[b,h,i,j] = cs[i][e(j)] - cs[i][s(j)], s=clip(j-16,0,64), e=clip(j+16,0,64)
// => wei==0 for j>=80; softmax tail folds into one weight * tail-sum of vp.

typedef __bf16 bf16x8 __attribute__((ext_vector_type(8)));
typedef float f32x4 __attribute__((ext_vector_type(4)));

#define AS1(p) ((__attribute__((address_space(1))) void*)(p))
#define AS3(p) ((__attribute__((address_space(3))) void*)(p))

// ---------------- fp32 -> bf16 convert (float4 per thread) ----------------
__global__ __launch_bounds__(256) void cvt_kernel(
    const float* __restrict__ s0, const float* __restrict__ s1,
    const float* __restrict__ s2, const float* __restrict__ s3,
    ushort4* __restrict__ dst, int n4)
{
  const float* s = blockIdx.y == 0 ? s0 : blockIdx.y == 1 ? s1
                 : blockIdx.y == 2 ? s2 : s3;
  int i = blockIdx.x * 256 + threadIdx.x;
  if (i >= n4) return;
  float4 v = ((const float4*)s)[i];
  union { ushort4 u; __hip_bfloat16 h[4]; } c;
  c.h[0] = __float2bfloat16(v.x); c.h[1] = __float2bfloat16(v.y);
  c.h[2] = __float2bfloat16(v.z); c.h[3] = __float2bfloat16(v.w);
  dst[(size_t)blockIdx.y * n4 + i] = c.u;
}

// ---------------- bf16 NT GEMM: C[m][n] = sum_k A[m][k]*Bw[n][k] ----------
// M x 1024 x 1024, 128x128 tile, BK=32, 4 waves each 64x64, 16x16x32 MFMA.
__device__ __forceinline__ void gemm_bt_body(
    const __hip_bfloat16* __restrict__ A, const __hip_bfloat16* __restrict__ Bw,
    float* __restrict__ C, const float* __restrict__ bias)
{
  const int N = 1024, K = 1024;
  __shared__ __align__(16) __hip_bfloat16 As[128 * 32];
  __shared__ __align__(16) __hip_bfloat16 Bs[128 * 32];
  const int t = threadIdx.x;
  const int wv = t >> 6, lane = t & 63;
  const int mBase = blockIdx.y * 128, nBase = blockIdx.x * 128;
  const int wRow = (wv >> 1) * 64, wCol = (wv & 1) * 64;
  const int mrow = lane & 15, kq = lane >> 4;

  f32x4 acc[4][4] = {};

  for (int k0 = 0; k0 < K; k0 += 32) {
    __syncthreads();  // prior compute done before LDS overwrite
#pragma unroll
    for (int tI = 0; tI < 2; ++tI) {
      int chunk = wv * 2 + tI;              // 0..7, 1024B each
      int byteOff = chunk * 1024 + lane * 16;
      int row = byteOff >> 6;               // 64B per 32-elem bf16 row
      int colEl = (byteOff & 63) >> 1;      // {0,8,16,24}
      const __hip_bfloat16* ga = A + (size_t)(mBase + row) * K + k0 + colEl;
      __builtin_amdgcn_global_load_lds(AS1((void*)ga), AS3(&As[chunk * 512]), 16, 0, 0);
      const __hip_bfloat16* gb = Bw + (size_t)(nBase + row) * K + k0 + colEl;
      __builtin_amdgcn_global_load_lds(AS1((void*)gb), AS3(&Bs[chunk * 512]), 16, 0, 0);
    }
    __syncthreads();  // drains vmcnt before barrier -> LDS tiles ready

    bf16x8 af[4], bf[4];
#pragma unroll
    for (int mi = 0; mi < 4; ++mi)
      af[mi] = *(const bf16x8*)&As[(wRow + mi * 16 + mrow) * 32 + kq * 8];
#pragma unroll
    for (int ni = 0; ni < 4; ++ni)
      bf[ni] = *(const bf16x8*)&Bs[(wCol + ni * 16 + mrow) * 32 + kq * 8];
#pragma unroll
    for (int mi = 0; mi < 4; ++mi)
#pragma unroll
      for (int ni = 0; ni < 4; ++ni)
        acc[mi][ni] = __builtin_amdgcn_mfma_f32_16x16x32_bf16(af[mi], bf[ni], acc[mi][ni], 0, 0, 0);
  }

  // C/D layout: col = lane&15, row = (lane>>4)*4 + r   [m89-verified]
#pragma unroll
  for (int mi = 0; mi < 4; ++mi)
#pragma unroll
    for (int ni = 0; ni < 4; ++ni)
#pragma unroll
      for (int r = 0; r < 4; ++r) {
        int row = mBase + wRow + mi * 16 + kq * 4 + r;
        int col = nBase + wCol + ni * 16 + mrow;
        float v = acc[mi][ni][r];
        if (bias) v += bias[col];
        C[(size_t)row * N + col] = v;
      }
}

__global__ __launch_bounds__(256) void qkv_gemm_kernel(
    const __hip_bfloat16* __restrict__ Xbf, const __hip_bfloat16* __restrict__ Wbf,
    float* __restrict__ OutP)
{
  const int z = blockIdx.z;
  gemm_bt_body(Xbf + (size_t)z * 4194304, Wbf + (size_t)z * 1048576,
               OutP + (size_t)z * 4194304, nullptr);
}

__global__ __launch_bounds__(256) void final_gemm_kernel(
    const __hip_bfloat16* __restrict__ Abf, const __hip_bfloat16* __restrict__ Wpbf,
    float* __restrict__ Out, const float* __restrict__ bias)
{
  gemm_bt_body(Abf, Wpbf, Out, bias);
}

// ---------------- tail sums: tails[b,h,d] = sum_{j=80..1023} vp[b,j,h,d] --
__global__ __launch_bounds__(256) void tail_sum_kernel(
    const float* __restrict__ VP, float* __restrict__ tails)
{
  int bh = blockIdx.x, b = bh >> 4, h = bh & 15;
  int d = threadIdx.x & 63, seg = threadIdx.x >> 6;
  float s = 0.0f;
  for (int j = 80 + seg; j < 1024; j += 4)
    s += VP[((size_t)(b * 1024 + j)) * 1024 + h * 64 + d];
  __shared__ float red[4][64];
  red[seg][d] = s;
  __syncthreads();
  if (threadIdx.x < 64)
    tails[bh * 64 + d] = red[0][d] + red[1][d] + red[2][d] + red[3][d];
}

// ---------------- attention: per (b,h, 64-row i-tile) ---------------------
__global__ __launch_bounds__(256) void attn_kernel(
    const float* __restrict__ QP, const float* __restrict__ KP,
    const float* __restrict__ VP, const float* __restrict__ tails,
    __hip_bfloat16* __restrict__ OUTA)
{
  const int b = blockIdx.z, h = blockIdx.y, i0 = blockIdx.x * 64;
  const int t = threadIdx.x, lane = t & 63, wv = t >> 6;

  __shared__ float vpl[80][64];    // vp rows 0..79 for this (b,h)
  __shared__ float csl[64][65];    // inclusive cumsum, padded
  __shared__ float wl[64][84];     // exp(wei-m), 16B-aligned rows
  __shared__ float scl[64], tlw[64], tail[64];

  // stage vp[0:80] and tail sums
  for (int idx = t; idx < 80 * 64; idx += 256) {
    int j = idx >> 6, d = idx & 63;
    vpl[j][d] = VP[((size_t)(b * 1024 + j)) * 1024 + h * 64 + d];
  }
  if (t < 64) tail[t] = tails[(b * 16 + h) * 64 + t];

  // p = qp*kp/8, inclusive cumsum over d (wave shuffle scan); wave wv owns 16 rows
  for (int ii = 0; ii < 16; ++ii) {
    int i = wv * 16 + ii;
    size_t row = ((size_t)(b * 1024 + i0 + i)) * 1024 + h * 64 + lane;
    float p = QP[row] * KP[row] * 0.125f;
#pragma unroll
    for (int delta = 1; delta < 64; delta <<= 1) {
      float up = __shfl_up(p, (unsigned)delta, 64);
      if (lane >= delta) p += up;
    }
    csl[i][lane] = p;
  }
  __syncthreads();

  // wei for j<80, softmax max/sum (tail logit = 0, count 944)
  {
    int i = t >> 2, jg = t & 3;
    float wloc[20];
    float mx = 0.0f;  // includes tail's wei=0
#pragma unroll
    for (int q = 0; q < 20; ++q) {
      int j = jg + 4 * q;
      int s = j - 16; s = s < 0 ? 0 : s;
      int e = j + 16; e = e > 64 ? 64 : e;
      float w = csl[i][e - 1] - (s > 0 ? csl[i][s - 1] : 0.0f);
      wloc[q] = w;
      mx = fmaxf(mx, w);
    }
    mx = fmaxf(mx, __shfl_xor(mx, 1, 64));
    mx = fmaxf(mx, __shfl_xor(mx, 2, 64));
    float sum = 0.0f;
#pragma unroll
    for (int q = 0; q < 20; ++q) {
      float e_ = __expf(wloc[q] - mx);
      wl[i][jg + 4 * q] = e_;
      sum += e_;
    }
    sum += __shfl_xor(sum, 1, 64);
    sum += __shfl_xor(sum, 2, 64);
    float tw = __expf(-mx);
    sum += 944.0f * tw;
    if (jg == 0) { scl[i] = 1.0f / sum; tlw[i] = tw / sum; }
  }
  __syncthreads();

  // out[i][d] = scl[i] * sum_j wl[i][j]*vpl[j][d] + tlw[i]*tail[d]
  {
    int d = lane;
    float acc[16];
#pragma unroll
    for (int ii = 0; ii < 16; ++ii) acc[ii] = 0.0f;
    for (int jq = 0; jq < 20; ++jq) {
      float v0 = vpl[4 * jq + 0][d], v1 = vpl[4 * jq + 1][d];
      float v2 = vpl[4 * jq + 2][d], v3 = vpl[4 * jq + 3][d];
#pragma unroll
      for (int ii = 0; ii < 16; ++ii) {
        int i = wv * 16 + ii;
        float4 w4 = *(const float4*)&wl[i][4 * jq];  // broadcast b128
        acc[ii] += w4.x * v0 + w4.y * v1 + w4.z * v2 + w4.w * v3;
      }
    }
#pragma unroll
    for (int ii = 0; ii < 16; ++ii) {
      int i = wv * 16 + ii;
      float o = acc[ii] * scl[i] + tlw[i] * tail[d];
      OUTA[((size_t)(b * 1024 + i0 + i)) * 1024 + h * 64 + d] = __float2bfloat16(o);
    }
  }
}

// ---------------- launch ---------------------------------------------------
extern "C" void kernel_launch(void* const* d_in, const int* in_sizes, int n_in,
                              void* d_out, int out_size, void* d_ws, size_t ws_size,
                              hipStream_t stream)
{
  (void)in_sizes; (void)n_in; (void)out_size; (void)ws_size;
  const float* q  = (const float*)d_in[0];
  const float* k  = (const float*)d_in[1];
  const float* v  = (const float*)d_in[2];
  const float* Wq = (const float*)d_in[3];
  const float* Wk = (const float*)d_in[4];
  const float* Wv = (const float*)d_in[5];
  const float* Wp = (const float*)d_in[6];
  const float* bp = (const float*)d_in[7];

  char* ws = (char*)d_ws;
  __hip_bfloat16* qkv_bf = (__hip_bfloat16*)(ws);              // 3 x 4M bf16 = 24 MB
  __hip_bfloat16* w_bf   = (__hip_bfloat16*)(ws + 25165824);   // 4 x 1M bf16 = 8 MB
  float*          QKVp   = (float*)(ws + 33554432);            // 3 x 4M f32 = 48 MB
  float*          tails  = (float*)(ws + 83886080);            // 16 KB
  __hip_bfloat16* OUTA   = (__hip_bfloat16*)(ws + 83902464);   // 4M bf16 = 8 MB
  float* out = (float*)d_out;

  cvt_kernel<<<dim3(4096, 3, 1), 256, 0, stream>>>(q, k, v, q, (ushort4*)qkv_bf, 1048576);
  cvt_kernel<<<dim3(1024, 4, 1), 256, 0, stream>>>(Wq, Wk, Wv, Wp, (ushort4*)w_bf, 262144);
  qkv_gemm_kernel<<<dim3(8, 32, 3), 256, 0, stream>>>(qkv_bf, w_bf, QKVp);
  tail_sum_kernel<<<dim3(64), 256, 0, stream>>>(QKVp + 2 * 4194304, tails);
  attn_kernel<<<dim3(16, 16, 4), 256, 0, stream>>>(QKVp, QKVp + 4194304,
                                                   QKVp + 2 * 4194304, tails, OUTA);
  final_gemm_kernel<<<dim3(8, 32, 1), 256, 0, stream>>>(OUTA, w_bf + 3 * 1048576, out, bp);
}

// Round 2
// 240.401 us; speedup vs baseline: 1.2675x; 1.2675x over previous
//
#include <hip/hip_runtime.h>
#include <hip/hip_bf16.h>
#include <stdint.h>

// B=4, T=1024, C=1024, H=16, D=64, ks=16
// wei[b,h,i,j] = cs[i][e(j)] - cs[i][s(j)], s=clip(j-16,0,64), e=clip(j+16,0,64)
// => wei==0 for j>=80; softmax tail folds into one weight * tail-sum of vp.

typedef __bf16 bf16x8 __attribute__((ext_vector_type(8)));
typedef float f32x4 __attribute__((ext_vector_type(4)));

#define AS1(p) ((__attribute__((address_space(1))) void*)(p))
#define AS3(p) ((__attribute__((address_space(3))) void*)(p))

// ---------------- fp32 -> bf16 convert (float4 per thread) ----------------
__global__ __launch_bounds__(256) void cvt_kernel(
    const float* __restrict__ s0, const float* __restrict__ s1,
    const float* __restrict__ s2, const float* __restrict__ s3,
    ushort4* __restrict__ dst, int n4)
{
  const float* s = blockIdx.y == 0 ? s0 : blockIdx.y == 1 ? s1
                 : blockIdx.y == 2 ? s2 : s3;
  int i = blockIdx.x * 256 + threadIdx.x;
  if (i >= n4) return;
  float4 v = ((const float4*)s)[i];
  union { ushort4 u; __hip_bfloat16 h[4]; } c;
  c.h[0] = __float2bfloat16(v.x); c.h[1] = __float2bfloat16(v.y);
  c.h[2] = __float2bfloat16(v.z); c.h[3] = __float2bfloat16(v.w);
  dst[(size_t)blockIdx.y * n4 + i] = c.u;
}

// ---------------- bf16 NT GEMM: C[m][n] = sum_k A[m][k]*Bw[n][k] ----------
// M x 1024 x 1024, 128x128 tile, BK=32, 4 waves each 64x64, 16x16x32 MFMA.
__device__ __forceinline__ void gemm_bt_body(
    const __hip_bfloat16* __restrict__ A, const __hip_bfloat16* __restrict__ Bw,
    float* __restrict__ C, const float* __restrict__ bias)
{
  const int N = 1024, K = 1024;
  __shared__ __align__(16) __hip_bfloat16 As[128 * 32];
  __shared__ __align__(16) __hip_bfloat16 Bs[128 * 32];
  const int t = threadIdx.x;
  const int wv = t >> 6, lane = t & 63;
  const int mBase = blockIdx.y * 128, nBase = blockIdx.x * 128;
  const int wRow = (wv >> 1) * 64, wCol = (wv & 1) * 64;
  const int mrow = lane & 15, kq = lane >> 4;

  f32x4 acc[4][4] = {};

  for (int k0 = 0; k0 < K; k0 += 32) {
    __syncthreads();  // prior compute done before LDS overwrite
#pragma unroll
    for (int tI = 0; tI < 2; ++tI) {
      int chunk = wv * 2 + tI;              // 0..7, 1024B each
      int byteOff = chunk * 1024 + lane * 16;
      int row = byteOff >> 6;               // 64B per 32-elem bf16 row
      int colEl = (byteOff & 63) >> 1;      // {0,8,16,24}
      const __hip_bfloat16* ga = A + (size_t)(mBase + row) * K + k0 + colEl;
      __builtin_amdgcn_global_load_lds(AS1((void*)ga), AS3(&As[chunk * 512]), 16, 0, 0);
      const __hip_bfloat16* gb = Bw + (size_t)(nBase + row) * K + k0 + colEl;
      __builtin_amdgcn_global_load_lds(AS1((void*)gb), AS3(&Bs[chunk * 512]), 16, 0, 0);
    }
    __syncthreads();  // drains vmcnt before barrier -> LDS tiles ready

    bf16x8 af[4], bf[4];
#pragma unroll
    for (int mi = 0; mi < 4; ++mi)
      af[mi] = *(const bf16x8*)&As[(wRow + mi * 16 + mrow) * 32 + kq * 8];
#pragma unroll
    for (int ni = 0; ni < 4; ++ni)
      bf[ni] = *(const bf16x8*)&Bs[(wCol + ni * 16 + mrow) * 32 + kq * 8];
#pragma unroll
    for (int mi = 0; mi < 4; ++mi)
#pragma unroll
      for (int ni = 0; ni < 4; ++ni)
        acc[mi][ni] = __builtin_amdgcn_mfma_f32_16x16x32_bf16(af[mi], bf[ni], acc[mi][ni], 0, 0, 0);
  }

  // C/D layout: col = lane&15, row = (lane>>4)*4 + r   [m89-verified]
#pragma unroll
  for (int mi = 0; mi < 4; ++mi)
#pragma unroll
    for (int ni = 0; ni < 4; ++ni)
#pragma unroll
      for (int r = 0; r < 4; ++r) {
        int row = mBase + wRow + mi * 16 + kq * 4 + r;
        int col = nBase + wCol + ni * 16 + mrow;
        float v = acc[mi][ni][r];
        if (bias) v += bias[col];
        C[(size_t)row * N + col] = v;
      }
}

__global__ __launch_bounds__(256) void qkv_gemm_kernel(
    const __hip_bfloat16* __restrict__ Xbf, const __hip_bfloat16* __restrict__ Wbf,
    float* __restrict__ OutP)
{
  const int z = blockIdx.z;
  gemm_bt_body(Xbf + (size_t)z * 4194304, Wbf + (size_t)z * 1048576,
               OutP + (size_t)z * 4194304, nullptr);
}

__global__ __launch_bounds__(256) void final_gemm_kernel(
    const __hip_bfloat16* __restrict__ Abf, const __hip_bfloat16* __restrict__ Wpbf,
    float* __restrict__ Out, const float* __restrict__ bias)
{
  gemm_bt_body(Abf, Wpbf, Out, bias);
}

// ------- tail partials: partial[bh*16+seg][d] = sum over 59 rows ----------
// j range [80,1024) split into 16 segs of 59 rows. 1024 blocks for occupancy.
__global__ __launch_bounds__(256) void tail_partial_kernel(
    const float* __restrict__ VP, float* __restrict__ partial)
{
  const int seg = blockIdx.x, bh = blockIdx.y;   // seg 0..15, bh 0..63
  const int b = bh >> 4, h = bh & 15;
  const int d = threadIdx.x & 63, wv = threadIdx.x >> 6;
  const int jBase = 80 + seg * 59;
  float s = 0.0f;
  for (int r = wv; r < 59; r += 4)
    s += VP[((size_t)(b * 1024 + jBase + r)) * 1024 + h * 64 + d];
  __shared__ float red[4][64];
  red[wv][d] = s;
  __syncthreads();
  if (threadIdx.x < 64)
    partial[(bh * 16 + seg) * 64 + threadIdx.x] =
        red[0][threadIdx.x] + red[1][threadIdx.x] + red[2][threadIdx.x] + red[3][threadIdx.x];
}

// ---------------- attention: per (b,h, 64-row i-tile) ---------------------
__global__ __launch_bounds__(256) void attn_kernel(
    const float* __restrict__ QP, const float* __restrict__ KP,
    const float* __restrict__ VP, const float* __restrict__ partial,
    __hip_bfloat16* __restrict__ OUTA)
{
  const int b = blockIdx.z, h = blockIdx.y, i0 = blockIdx.x * 64;
  const int t = threadIdx.x, lane = t & 63, wv = t >> 6;

  __shared__ float vpl[80][64];    // vp rows 0..79 for this (b,h)
  __shared__ float csl[64][65];    // inclusive cumsum, padded
  __shared__ float wl[64][84];     // exp(wei-m), 16B-aligned rows
  __shared__ float scl[64], tlw[64], tail[64];

  // stage vp[0:80]; reduce 16 tail partials for this (b,h)
  for (int idx = t; idx < 80 * 64; idx += 256) {
    int j = idx >> 6, d = idx & 63;
    vpl[j][d] = VP[((size_t)(b * 1024 + j)) * 1024 + h * 64 + d];
  }
  if (t < 64) {
    const float* pp = partial + (b * 16 + h) * 16 * 64 + t;
    float s = 0.0f;
#pragma unroll
    for (int seg = 0; seg < 16; ++seg) s += pp[seg * 64];
    tail[t] = s;
  }

  // p = qp*kp/8, inclusive cumsum over d (wave shuffle scan); wave wv owns 16 rows
  for (int ii = 0; ii < 16; ++ii) {
    int i = wv * 16 + ii;
    size_t row = ((size_t)(b * 1024 + i0 + i)) * 1024 + h * 64 + lane;
    float p = QP[row] * KP[row] * 0.125f;
#pragma unroll
    for (int delta = 1; delta < 64; delta <<= 1) {
      float up = __shfl_up(p, (unsigned)delta, 64);
      if (lane >= delta) p += up;
    }
    csl[i][lane] = p;
  }
  __syncthreads();

  // wei for j<80, softmax max/sum (tail logit = 0, count 944)
  {
    int i = t >> 2, jg = t & 3;
    float wloc[20];
    float mx = 0.0f;  // includes tail's wei=0
#pragma unroll
    for (int q = 0; q < 20; ++q) {
      int j = jg + 4 * q;
      int s = j - 16; s = s < 0 ? 0 : s;
      int e = j + 16; e = e > 64 ? 64 : e;
      float w = csl[i][e - 1] - (s > 0 ? csl[i][s - 1] : 0.0f);
      wloc[q] = w;
      mx = fmaxf(mx, w);
    }
    mx = fmaxf(mx, __shfl_xor(mx, 1, 64));
    mx = fmaxf(mx, __shfl_xor(mx, 2, 64));
    float sum = 0.0f;
#pragma unroll
    for (int q = 0; q < 20; ++q) {
      float e_ = __expf(wloc[q] - mx);
      wl[i][jg + 4 * q] = e_;
      sum += e_;
    }
    sum += __shfl_xor(sum, 1, 64);
    sum += __shfl_xor(sum, 2, 64);
    float tw = __expf(-mx);
    sum += 944.0f * tw;
    if (jg == 0) { scl[i] = 1.0f / sum; tlw[i] = tw / sum; }
  }
  __syncthreads();

  // out[i][d] = scl[i] * sum_j wl[i][j]*vpl[j][d] + tlw[i]*tail[d]
  {
    int d = lane;
    float acc[16];
#pragma unroll
    for (int ii = 0; ii < 16; ++ii) acc[ii] = 0.0f;
    for (int jq = 0; jq < 20; ++jq) {
      float v0 = vpl[4 * jq + 0][d], v1 = vpl[4 * jq + 1][d];
      float v2 = vpl[4 * jq + 2][d], v3 = vpl[4 * jq + 3][d];
#pragma unroll
      for (int ii = 0; ii < 16; ++ii) {
        int i = wv * 16 + ii;
        float4 w4 = *(const float4*)&wl[i][4 * jq];  // broadcast b128
        acc[ii] += w4.x * v0 + w4.y * v1 + w4.z * v2 + w4.w * v3;
      }
    }
#pragma unroll
    for (int ii = 0; ii < 16; ++ii) {
      int i = wv * 16 + ii;
      float o = acc[ii] * scl[i] + tlw[i] * tail[d];
      OUTA[((size_t)(b * 1024 + i0 + i)) * 1024 + h * 64 + d] = __float2bfloat16(o);
    }
  }
}

// ---------------- launch ---------------------------------------------------
extern "C" void kernel_launch(void* const* d_in, const int* in_sizes, int n_in,
                              void* d_out, int out_size, void* d_ws, size_t ws_size,
                              hipStream_t stream)
{
  (void)in_sizes; (void)n_in; (void)out_size; (void)ws_size;
  const float* q  = (const float*)d_in[0];
  const float* k  = (const float*)d_in[1];
  const float* v  = (const float*)d_in[2];
  const float* Wq = (const float*)d_in[3];
  const float* Wk = (const float*)d_in[4];
  const float* Wv = (const float*)d_in[5];
  const float* Wp = (const float*)d_in[6];
  const float* bp = (const float*)d_in[7];

  char* ws = (char*)d_ws;
  __hip_bfloat16* qkv_bf = (__hip_bfloat16*)(ws);              // 3 x 4M bf16 = 24 MB
  __hip_bfloat16* w_bf   = (__hip_bfloat16*)(ws + 25165824);   // 4 x 1M bf16 = 8 MB
  float*          QKVp   = (float*)(ws + 33554432);            // 3 x 4M f32 = 48 MB
  // tail partials reuse the qkv_bf region (dead after qkv_gemm): 1024*64*4 = 256 KB
  float*          partial = (float*)(ws);
  __hip_bfloat16* OUTA   = (__hip_bfloat16*)(ws + 83902464);   // 4M bf16 = 8 MB
  float* out = (float*)d_out;

  cvt_kernel<<<dim3(4096, 3, 1), 256, 0, stream>>>(q, k, v, q, (ushort4*)qkv_bf, 1048576);
  cvt_kernel<<<dim3(1024, 4, 1), 256, 0, stream>>>(Wq, Wk, Wv, Wp, (ushort4*)w_bf, 262144);
  qkv_gemm_kernel<<<dim3(8, 32, 3), 256, 0, stream>>>(qkv_bf, w_bf, QKVp);
  tail_partial_kernel<<<dim3(16, 64), 256, 0, stream>>>(QKVp + 2 * 4194304, partial);
  attn_kernel<<<dim3(16, 16, 4), 256, 0, stream>>>(QKVp, QKVp + 4194304,
                                                   QKVp + 2 * 4194304, partial, OUTA);
  final_gemm_kernel<<<dim3(8, 32, 1), 256, 0, stream>>>(OUTA, w_bf + 3 * 1048576, out, bp);
}

// Round 3
// 204.505 us; speedup vs baseline: 1.4900x; 1.1755x over previous
//
#include <hip/hip_runtime.h>
#include <hip/hip_bf16.h>
#include <stdint.h>

// B=4, T=1024, C=1024, H=16, D=64, ks=16
// wei[b,h,i,j] = cs[i][e(j)] - cs[i][s(j)], s=clip(j-16,0,64), e=clip(j+16,0,64)
// => wei==0 for j>=80; softmax tail folds into one weight * tail-sum of vp.
// R2: bf16 QKV intermediates; MFMA PV in attn; XCD swizzle on GEMM tiles.

typedef __bf16 bf16x8 __attribute__((ext_vector_type(8)));
typedef float f32x4 __attribute__((ext_vector_type(4)));

#define AS1(p) ((__attribute__((address_space(1))) void*)(p))
#define AS3(p) ((__attribute__((address_space(3))) void*)(p))

// ---------------- fp32 -> bf16 convert (float4 per thread) ----------------
__global__ __launch_bounds__(256) void cvt_kernel(
    const float* __restrict__ s0, const float* __restrict__ s1,
    const float* __restrict__ s2, const float* __restrict__ s3,
    ushort4* __restrict__ dst, int n4)
{
  const float* s = blockIdx.y == 0 ? s0 : blockIdx.y == 1 ? s1
                 : blockIdx.y == 2 ? s2 : s3;
  int i = blockIdx.x * 256 + threadIdx.x;
  if (i >= n4) return;
  float4 v = ((const float4*)s)[i];
  union { ushort4 u; __hip_bfloat16 h[4]; } c;
  c.h[0] = __float2bfloat16(v.x); c.h[1] = __float2bfloat16(v.y);
  c.h[2] = __float2bfloat16(v.z); c.h[3] = __float2bfloat16(v.w);
  dst[(size_t)blockIdx.y * n4 + i] = c.u;
}

// ---------------- bf16 NT GEMM: C[m][n] = sum_k A[m][k]*Bw[n][k] ----------
// 128x128 tile, BK=32, 4 waves each 64x64, 16x16x32 MFMA. Templated output.
template <typename OutT>
__device__ __forceinline__ void gemm_bt_body(
    const __hip_bfloat16* __restrict__ A, const __hip_bfloat16* __restrict__ Bw,
    OutT* __restrict__ C, const float* __restrict__ bias, int mBase, int nBase)
{
  const int N = 1024, K = 1024;
  __shared__ __align__(16) __hip_bfloat16 As[128 * 32];
  __shared__ __align__(16) __hip_bfloat16 Bs[128 * 32];
  const int t = threadIdx.x;
  const int wv = t >> 6, lane = t & 63;
  const int wRow = (wv >> 1) * 64, wCol = (wv & 1) * 64;
  const int mrow = lane & 15, kq = lane >> 4;

  f32x4 acc[4][4] = {};

  for (int k0 = 0; k0 < K; k0 += 32) {
    __syncthreads();  // prior compute done before LDS overwrite
#pragma unroll
    for (int tI = 0; tI < 2; ++tI) {
      int chunk = wv * 2 + tI;              // 0..7, 1024B each
      int byteOff = chunk * 1024 + lane * 16;
      int row = byteOff >> 6;               // 64B per 32-elem bf16 row
      int colEl = (byteOff & 63) >> 1;      // {0,8,16,24}
      const __hip_bfloat16* ga = A + (size_t)(mBase + row) * K + k0 + colEl;
      __builtin_amdgcn_global_load_lds(AS1((void*)ga), AS3(&As[chunk * 512]), 16, 0, 0);
      const __hip_bfloat16* gb = Bw + (size_t)(nBase + row) * K + k0 + colEl;
      __builtin_amdgcn_global_load_lds(AS1((void*)gb), AS3(&Bs[chunk * 512]), 16, 0, 0);
    }
    __syncthreads();  // drains vmcnt before barrier -> LDS tiles ready

    bf16x8 af[4], bf[4];
#pragma unroll
    for (int mi = 0; mi < 4; ++mi)
      af[mi] = *(const bf16x8*)&As[(wRow + mi * 16 + mrow) * 32 + kq * 8];
#pragma unroll
    for (int ni = 0; ni < 4; ++ni)
      bf[ni] = *(const bf16x8*)&Bs[(wCol + ni * 16 + mrow) * 32 + kq * 8];
#pragma unroll
    for (int mi = 0; mi < 4; ++mi)
#pragma unroll
      for (int ni = 0; ni < 4; ++ni)
        acc[mi][ni] = __builtin_amdgcn_mfma_f32_16x16x32_bf16(af[mi], bf[ni], acc[mi][ni], 0, 0, 0);
  }

  // C/D layout: col = lane&15, row = (lane>>4)*4 + r   [m89-verified]
#pragma unroll
  for (int mi = 0; mi < 4; ++mi)
#pragma unroll
    for (int ni = 0; ni < 4; ++ni)
#pragma unroll
      for (int r = 0; r < 4; ++r) {
        int row = mBase + wRow + mi * 16 + kq * 4 + r;
        int col = nBase + wCol + ni * 16 + mrow;
        float v = acc[mi][ni][r];
        if (bias) v += bias[col];
        if constexpr (__is_same(OutT, __hip_bfloat16))
          C[(size_t)row * N + col] = __float2bfloat16(v);
        else
          C[(size_t)row * N + col] = v;
      }
}

// XCD swizzle: linear l -> (z, m, n) with m == l (mod 8) so each XCD (l%8)
// touches only 4 distinct A-strips (A fetched once per strip device-wide).
__global__ __launch_bounds__(256) void qkv_gemm_kernel(
    const __hip_bfloat16* __restrict__ Xbf, const __hip_bfloat16* __restrict__ Wbf,
    __hip_bfloat16* __restrict__ OutP)
{
  int l = blockIdx.x;            // 0..767
  int mm = l % 96;
  int z = mm >> 5, m = mm & 31, n = l / 96;
  gemm_bt_body<__hip_bfloat16>(Xbf + (size_t)z * 4194304, Wbf + (size_t)z * 1048576,
                               OutP + (size_t)z * 4194304, nullptr, m * 128, n * 128);
}

__global__ __launch_bounds__(256) void final_gemm_kernel(
    const __hip_bfloat16* __restrict__ Abf, const __hip_bfloat16* __restrict__ Wpbf,
    float* __restrict__ Out, const float* __restrict__ bias)
{
  int l = blockIdx.x;            // 0..255
  int m = l & 31, n = l >> 5;
  gemm_bt_body<float>(Abf, Wpbf, Out, bias, m * 128, n * 128);
}

// ------- tail partials: partial[bh*16+seg][d] = sum over 59 rows ----------
__global__ __launch_bounds__(256) void tail_partial_kernel(
    const __hip_bfloat16* __restrict__ VP, float* __restrict__ partial)
{
  const int seg = blockIdx.x, bh = blockIdx.y;   // seg 0..15, bh 0..63
  const int b = bh >> 4, h = bh & 15;
  const int d = threadIdx.x & 63, wv = threadIdx.x >> 6;
  const int jBase = 80 + seg * 59;
  float s = 0.0f;
  for (int r = wv; r < 59; r += 4)
    s += __bfloat162float(VP[((size_t)(b * 1024 + jBase + r)) * 1024 + h * 64 + d]);
  __shared__ float red[4][64];
  red[wv][d] = s;
  __syncthreads();
  if (threadIdx.x < 64)
    partial[(bh * 16 + seg) * 64 + threadIdx.x] =
        red[0][threadIdx.x] + red[1][threadIdx.x] + red[2][threadIdx.x] + red[3][threadIdx.x];
}

// ---------------- attention: per (b,h, 64-row i-tile) ---------------------
// Phases: A) qp*kp cumsum (f32 shuffle scan)  B) softmax -> wl bf16 in LDS
// C) vp[0:80] transposed bf16 in LDS  D) PV via MFMA (64x96x64).
__global__ __launch_bounds__(256) void attn_kernel(
    const __hip_bfloat16* __restrict__ QP, const __hip_bfloat16* __restrict__ KP,
    const __hip_bfloat16* __restrict__ VP, const float* __restrict__ partial,
    __hip_bfloat16* __restrict__ OUTA)
{
  const int b = blockIdx.z, h = blockIdx.y, i0 = blockIdx.x * 64;
  const int t = threadIdx.x, lane = t & 63, wv = t >> 6;

  __shared__ float csl[64][65];                       // inclusive cumsum, padded
  __shared__ __align__(16) __hip_bfloat16 wlb[64][96]; // exp(wei-m) bf16, A-operand rows [i][j]
  __shared__ __align__(16) __hip_bfloat16 vpt[64][104];// vp^T bf16, B-operand rows [d][j], 16B-aligned stride
  __shared__ float scl[64], tlw[64], tail[64];

  // tail reduce for this (b,h)
  if (t < 64) {
    const float* pp = partial + (b * 16 + h) * 16 * 64 + t;
    float s = 0.0f;
#pragma unroll
    for (int seg = 0; seg < 16; ++seg) s += pp[seg * 64];
    tail[t] = s;
  }

  // stage vp^T[d][j] for j<80; zero-pad j=80..95
  for (int idx = t; idx < 80 * 64; idx += 256) {
    int j = idx >> 6, d = idx & 63;
    vpt[d][j] = VP[((size_t)(b * 1024 + j)) * 1024 + h * 64 + d];
  }
  for (int idx = t; idx < 64 * 16; idx += 256) {
    int d = idx >> 4, j = 80 + (idx & 15);
    vpt[d][j] = __float2bfloat16(0.0f);
  }

  // phase A: p = qp*kp/8, inclusive cumsum over d (wave shuffle scan)
  for (int ii = 0; ii < 16; ++ii) {
    int i = wv * 16 + ii;
    size_t row = ((size_t)(b * 1024 + i0 + i)) * 1024 + h * 64 + lane;
    float p = __bfloat162float(QP[row]) * __bfloat162float(KP[row]) * 0.125f;
#pragma unroll
    for (int delta = 1; delta < 64; delta <<= 1) {
      float up = __shfl_up(p, (unsigned)delta, 64);
      if (lane >= delta) p += up;
    }
    csl[i][lane] = p;
  }
  __syncthreads();

  // phase B: wei for j<80, softmax max/sum (tail logit = 0, count 944)
  {
    int i = t >> 2, jg = t & 3;
    float wloc[20];
    float mx = 0.0f;  // includes tail's wei=0
#pragma unroll
    for (int q = 0; q < 20; ++q) {
      int j = jg + 4 * q;
      int s = j - 16; s = s < 0 ? 0 : s;
      int e = j + 16; e = e > 64 ? 64 : e;
      float w = csl[i][e - 1] - (s > 0 ? csl[i][s - 1] : 0.0f);
      wloc[q] = w;
      mx = fmaxf(mx, w);
    }
    mx = fmaxf(mx, __shfl_xor(mx, 1, 64));
    mx = fmaxf(mx, __shfl_xor(mx, 2, 64));
    float sum = 0.0f;
#pragma unroll
    for (int q = 0; q < 20; ++q) {
      float e_ = __expf(wloc[q] - mx);
      wlb[i][jg + 4 * q] = __float2bfloat16(e_);
      sum += e_;
    }
#pragma unroll
    for (int q = 0; q < 4; ++q)      // zero pad j = 80..95
      wlb[i][80 + jg + 4 * q] = __float2bfloat16(0.0f);
    sum += __shfl_xor(sum, 1, 64);
    sum += __shfl_xor(sum, 2, 64);
    float tw = __expf(-mx);
    sum += 944.0f * tw;
    if (jg == 0) { scl[i] = 1.0f / sum; tlw[i] = tw / sum; }
  }
  __syncthreads();

  // phase D: O[i][d] = sum_j wl[i][j] * vpt[d][j] via MFMA (M=64,N=64,K=96)
  {
    const int mh = (wv >> 1) * 32, nh = (wv & 1) * 32;
    const int mrow = lane & 15, kq = lane >> 4;
    f32x4 acc[2][2] = {};
#pragma unroll
    for (int k0 = 0; k0 < 96; k0 += 32) {
      bf16x8 af[2], bf[2];
#pragma unroll
      for (int mi = 0; mi < 2; ++mi)
        af[mi] = *(const bf16x8*)&wlb[mh + mi * 16 + mrow][k0 + kq * 8];
#pragma unroll
      for (int ni = 0; ni < 2; ++ni)
        bf[ni] = *(const bf16x8*)&vpt[nh + ni * 16 + mrow][k0 + kq * 8];
#pragma unroll
      for (int mi = 0; mi < 2; ++mi)
#pragma unroll
        for (int ni = 0; ni < 2; ++ni)
          acc[mi][ni] = __builtin_amdgcn_mfma_f32_16x16x32_bf16(af[mi], bf[ni], acc[mi][ni], 0, 0, 0);
    }
#pragma unroll
    for (int mi = 0; mi < 2; ++mi)
#pragma unroll
      for (int ni = 0; ni < 2; ++ni)
#pragma unroll
        for (int r = 0; r < 4; ++r) {
          int i = mh + mi * 16 + kq * 4 + r;
          int d = nh + ni * 16 + mrow;
          float o = acc[mi][ni][r] * scl[i] + tlw[i] * tail[d];
          OUTA[((size_t)(b * 1024 + i0 + i)) * 1024 + h * 64 + d] = __float2bfloat16(o);
        }
  }
}

// ---------------- launch ---------------------------------------------------
extern "C" void kernel_launch(void* const* d_in, const int* in_sizes, int n_in,
                              void* d_out, int out_size, void* d_ws, size_t ws_size,
                              hipStream_t stream)
{
  (void)in_sizes; (void)n_in; (void)out_size; (void)ws_size;
  const float* q  = (const float*)d_in[0];
  const float* k  = (const float*)d_in[1];
  const float* v  = (const float*)d_in[2];
  const float* Wq = (const float*)d_in[3];
  const float* Wk = (const float*)d_in[4];
  const float* Wv = (const float*)d_in[5];
  const float* Wp = (const float*)d_in[6];
  const float* bp = (const float*)d_in[7];

  char* ws = (char*)d_ws;
  __hip_bfloat16* qkv_bf = (__hip_bfloat16*)(ws);              // 3 x 4M bf16 = 24 MB
  __hip_bfloat16* w_bf   = (__hip_bfloat16*)(ws + 25165824);   // 4 x 1M bf16 = 8 MB
  __hip_bfloat16* QKVpb  = (__hip_bfloat16*)(ws + 33554432);   // 3 x 4M bf16 = 24 MB
  __hip_bfloat16* OUTA   = (__hip_bfloat16*)(ws + 58720256);   // 4M bf16 = 8 MB
  // tail partials reuse qkv_bf region (dead after qkv_gemm): 1024*64*4 = 256 KB
  float* partial = (float*)(ws);
  float* out = (float*)d_out;

  cvt_kernel<<<dim3(4096, 3, 1), 256, 0, stream>>>(q, k, v, q, (ushort4*)qkv_bf, 1048576);
  cvt_kernel<<<dim3(1024, 4, 1), 256, 0, stream>>>(Wq, Wk, Wv, Wp, (ushort4*)w_bf, 262144);
  qkv_gemm_kernel<<<dim3(768), 256, 0, stream>>>(qkv_bf, w_bf, QKVpb);
  tail_partial_kernel<<<dim3(16, 64), 256, 0, stream>>>(QKVpb + (size_t)2 * 4194304, partial);
  attn_kernel<<<dim3(16, 16, 4), 256, 0, stream>>>(QKVpb, QKVpb + 4194304,
                                                   QKVpb + (size_t)2 * 4194304, partial, OUTA);
  final_gemm_kernel<<<dim3(256), 256, 0, stream>>>(OUTA, w_bf + (size_t)3 * 1048576, out, bp);
}